// Round 8
// baseline (301.110 us; speedup 1.0000x reference)
//
#include <hip/hip_runtime.h>
#include <hip/hip_bf16.h>

#define C 128
#define HW 4096
#define NPOS 65536
#define K 1024
#define MB 128           // positions per block
#define NBLK (NPOS/MB)   // 512
#define RS 136           // zt padded row stride in bf16 elems (272 B)
#define RSB 320          // codebook image row stride BYTES (64B-aligned segments)
#define CHK 64           // codes per chunk
#define NCH (K/CHK)      // 16
#define CHB (CHK*RSB)    // 20480 bytes per chunk
#define NRM_OFF 327680   // fp32 norm table offset within img (4 KB)

#define ZQ_OFF 0
#define LOSS_OFF 8388608
#define IDX_OFF 8388609
#define COMMIT_OFF 8454145
#define CODE_OFF 8454146

#define WS_IMG_OFF 8192  // codebook image at d_ws + 8192: 320 KB rows + 4 KB norms

typedef __bf16 bf16x8 __attribute__((ext_vector_type(8)));
typedef float f32x4 __attribute__((ext_vector_type(4)));
typedef unsigned short u16x8 __attribute__((ext_vector_type(8)));

// Padded bf16 codebook image: row k = 128 bf16 at 320B stride; norms
// ||e_k||^2+1 in a separate contiguous fp32 table at NRM_OFF (staged to LDS).
// Block 0 zeroes the loss accumulator (replaces the memset dispatch).
__global__ void vq_prep(const float* __restrict__ emb, unsigned char* __restrict__ img,
                        float* __restrict__ S) {
    int k = blockIdx.x;
    int l = threadIdx.x;            // 64 threads
    if (k == 0 && l == 0) S[0] = 0.0f;
    float v0 = emb[k * C + l];
    float v1 = emb[k * C + 64 + l];
    __hip_bfloat16 h0 = __float2bfloat16(v0);
    __hip_bfloat16 h1 = __float2bfloat16(v1);
    unsigned short* row = (unsigned short*)(img + (size_t)k * RSB);
    row[l] = *(unsigned short*)&h0;
    row[64 + l] = *(unsigned short*)&h1;
    float s = v0 * v0 + v1 * v1;
    #pragma unroll
    for (int off = 32; off; off >>= 1) s += __shfl_down(s, off);
    if (l == 0) *(float*)(img + NRM_OFF + (size_t)k * 4) = s + 1.0f;
}

// r7 post-mortem: scheduler targets 8 waves/EU (64 VGPR) because 37KB LDS
// would allow 4 blocks/CU; the pinned A-array then SPILLS to scratch
// (FETCH/WRITE +250MB). Fix: force the occupancy target to 4 waves/EU
// (128-VGPR budget) via waves_per_eu(4,4) AND a hardware LDS cap (~60KB ->
// max 2 blocks/CU), and shrink per-wave state with a 4M x 2N split:
// A = 32 VGPRs pinned, best 8, bf 32 + acc 16 transient -> ~105 <= 128.
__global__ __attribute__((amdgpu_flat_work_group_size(512, 512), amdgpu_waves_per_eu(4, 4)))
void vq_main(const float* __restrict__ z, const float* __restrict__ emb,
             const unsigned char* __restrict__ img,
             float* __restrict__ out, float* __restrict__ S) {
    __shared__ __align__(16) unsigned short zt[MB * RS];  // 34816 B
    __shared__ __align__(16) float norm_lds[K];           // 4096 B
    __shared__ unsigned int wbest[2][MB];                 // 1024 B
    __shared__ unsigned short idxs[MB];                   // 256 B
    __shared__ float lred[8];
    __shared__ unsigned char occ_pad[20480];              // occupancy cap: ~60KB total
    // keep-alive for occ_pad: opaque never-true condition
    {
        unsigned int zz0 = 0;
        asm volatile("" : "+s"(zz0));
        if (zz0) occ_pad[0] = (unsigned char)zz0;
    }

    const int t = threadIdx.x;
    const int w = t >> 6;
    const int lane = t & 63;
    const int nn = lane & 15;      // MFMA: A row m / B col n / C col
    const int q = lane >> 4;       // quad
    const int wm = w >> 1;         // M-quarter: positions wm*32..+31
    const int wn = w & 1;          // N-half: codes wn*32..+31 of each chunk

    const int blk = blockIdx.x;
    const int n0g = blk * MB;
    const int b = n0g >> 12;
    const int hw0 = n0g & (HW - 1);
    const float* zg = z + (size_t)b * C * HW + hw0;

    // stage norms -> LDS (4 KB, waves 0..3, one 16B global_load_lds each)
    if (w < 4) {
        __builtin_amdgcn_global_load_lds(
            (const __attribute__((address_space(1))) unsigned int*)(img + NRM_OFF + w * 1024 + lane * 16),
            (__attribute__((address_space(3))) unsigned int*)((unsigned char*)norm_lds + w * 1024),
            16, 0, 0);
    }

    // stage z tile -> LDS bf16 [pos][c] (float4 along pos, register transpose)
    {
        const int pos4 = (t & 31) * 4;
        const int c0 = (t >> 5) * 8;
        float4 fv[8];
        #pragma unroll
        for (int i = 0; i < 8; ++i)
            fv[i] = *(const float4*)&zg[(size_t)(c0 + i) * HW + pos4];
        #pragma unroll
        for (int j = 0; j < 4; ++j) {
            u16x8 pk;
            #pragma unroll
            for (int i = 0; i < 8; ++i) {
                float f = (j == 0) ? fv[i].x : (j == 1) ? fv[i].y
                        : (j == 2) ? fv[i].z : fv[i].w;
                __hip_bfloat16 h = __float2bfloat16(f);
                pk[i] = *(unsigned short*)&h;
            }
            *(u16x8*)&zt[(pos4 + j) * RS + c0] = pk;
        }
    }
    __syncthreads();   // covers zt ds_writes AND norm global_load_lds drain

    // A fragments: 2 M-tiles x 4 K-steps = 32 VGPRs, pinned resident
    bf16x8 a[2][4];
    #pragma unroll
    for (int mt = 0; mt < 2; ++mt)
        #pragma unroll
        for (int ks = 0; ks < 4; ++ks) {
            a[mt][ks] = *(bf16x8*)&zt[(wm * 32 + mt * 16 + nn) * RS + ks * 32 + q * 8];
            asm volatile("" : "+v"(*(f32x4*)&a[mt][ks]));
        }

    unsigned int best[2][4];
    #pragma unroll
    for (int mt = 0; mt < 2; ++mt)
        #pragma unroll
        for (int r = 0; r < 4; ++r) best[mt][r] = 0xFFFFFFFFu;

    // per-lane B pointers: lane (nn,q) reads quarter-rows of codes
    // wn*32+nn (nt=0) and wn*32+16+nn (nt=1) of every chunk
    const unsigned char* pb0 = img + (size_t)(wn * 32 + nn) * RSB + q * 16;
    const unsigned char* pb1 = pb0 + (size_t)16 * RSB;

    for (int ch = 0; ch < NCH; ++ch) {
        bf16x8 bf0[4], bf1[4];
        #pragma unroll
        for (int ks = 0; ks < 4; ++ks) {
            bf0[ks] = *(const bf16x8*)(pb0 + ks * 64);
            bf1[ks] = *(const bf16x8*)(pb1 + ks * 64);
        }
        const float en0 = norm_lds[ch * CHK + wn * 32 + nn];
        const float en1 = norm_lds[ch * CHK + wn * 32 + 16 + nn];
        const unsigned int code0 = (unsigned int)(ch * CHK + wn * 32 + nn);

        f32x4 acc0[2], acc1[2];
        #pragma unroll
        for (int mt = 0; mt < 2; ++mt) {
            acc0[mt] = (f32x4){0.f, 0.f, 0.f, 0.f};
            acc1[mt] = (f32x4){0.f, 0.f, 0.f, 0.f};
        }
        #pragma unroll
        for (int ks = 0; ks < 4; ++ks)
            #pragma unroll
            for (int mt = 0; mt < 2; ++mt) {
                acc0[mt] = __builtin_amdgcn_mfma_f32_16x16x32_bf16(a[mt][ks], bf0[ks], acc0[mt], 0, 0, 0);
                acc1[mt] = __builtin_amdgcn_mfma_f32_16x16x32_bf16(a[mt][ks], bf1[ks], acc1[mt], 0, 0, 0);
            }

        // packed argmin: score' = (enorm+1) - 2*dot (always ~1.0 > 0),
        // clear low 10 mantissa bits, OR in code; u32 min == float min + tie-low.
        #pragma unroll
        for (int mt = 0; mt < 2; ++mt)
            #pragma unroll
            for (int r = 0; r < 4; ++r) {
                float s0 = fmaf(acc0[mt][r], -2.0f, en0);
                float s1 = fmaf(acc1[mt][r], -2.0f, en1);
                unsigned int u0 = (__float_as_uint(s0) & ~1023u) | code0;
                unsigned int u1 = (__float_as_uint(s1) & ~1023u) | (code0 + 16u);
                best[mt][r] = min(best[mt][r], min(u0, u1));
            }
        pb0 += CHB; pb1 += CHB;
    }

    // in-wave reduce over the 16 code-columns (xor lanes 1,2,4,8 stay in quad)
    #pragma unroll
    for (int mt = 0; mt < 2; ++mt)
        #pragma unroll
        for (int r = 0; r < 4; ++r) {
            unsigned int v = best[mt][r];
            v = min(v, (unsigned int)__shfl_xor((int)v, 1));
            v = min(v, (unsigned int)__shfl_xor((int)v, 2));
            v = min(v, (unsigned int)__shfl_xor((int)v, 4));
            v = min(v, (unsigned int)__shfl_xor((int)v, 8));
            if (nn == 0) wbest[wn][wm * 32 + mt * 16 + q * 4 + r] = v;
        }
    __syncthreads();

    if (t < MB) {
        unsigned int v = min(wbest[0][t], wbest[1][t]);
        unsigned int code = v & 1023u;
        idxs[t] = (unsigned short)code;
        out[IDX_OFF + n0g + t] = (float)code;
    }
    __syncthreads();

    // epilogue: per-position emb gather, register transpose, float4 z_q
    // stores along pos, exact fp32 loss from the same bf16 zt values
    {
        const int pos4 = (t & 31) * 4;
        const int c0 = (t >> 5) * 8;
        float* og = out + ZQ_OFF + (size_t)b * C * HW + hw0;
        float ev[4][8];
        float ls = 0.f;
        #pragma unroll
        for (int j = 0; j < 4; ++j) {
            const int pos = pos4 + j;
            const float* erow = emb + (size_t)idxs[pos] * C;
            float4 e0 = *(const float4*)&erow[c0];
            float4 e1 = *(const float4*)&erow[c0 + 4];
            ev[j][0] = e0.x; ev[j][1] = e0.y; ev[j][2] = e0.z; ev[j][3] = e0.w;
            ev[j][4] = e1.x; ev[j][5] = e1.y; ev[j][6] = e1.z; ev[j][7] = e1.w;
            u16x8 zz = *(u16x8*)&zt[pos * RS + c0];
            #pragma unroll
            for (int i = 0; i < 8; ++i) {
                float zf = __uint_as_float((unsigned int)zz[i] << 16);
                float d = zf - ev[j][i];
                ls += d * d;
            }
        }
        #pragma unroll
        for (int i = 0; i < 8; ++i) {
            float4 v = { ev[0][i], ev[1][i], ev[2][i], ev[3][i] };
            *(float4*)&og[(size_t)(c0 + i) * HW + pos4] = v;
        }
        #pragma unroll
        for (int off = 32; off; off >>= 1) ls += __shfl_down(ls, off);
        if (lane == 0) lred[w] = ls;
    }
    __syncthreads();
    if (t == 0) {
        float bs = 0.f;
        #pragma unroll
        for (int i = 0; i < 8; ++i) bs += lred[i];
        atomicAdd(S, bs);
    }
}

__global__ void vq_final(const float* __restrict__ S, float* __restrict__ out) {
    float s = *S;
    out[LOSS_OFF] = 1.25f * s;
    out[COMMIT_OFF] = 0.25f * s;
    out[CODE_OFF] = s;
}

extern "C" void kernel_launch(void* const* d_in, const int* in_sizes, int n_in,
                              void* d_out, int out_size, void* d_ws, size_t ws_size,
                              hipStream_t stream) {
    const float* z = (const float*)d_in[0];
    const float* emb = (const float*)d_in[1];
    float* out = (float*)d_out;
    float* S = (float*)d_ws;
    unsigned char* img = (unsigned char*)d_ws + WS_IMG_OFF;   // needs ~340 KB of ws

    vq_prep<<<K, 64, 0, stream>>>(emb, img, S);
    vq_main<<<NBLK, 512, 0, stream>>>(z, emb, img, out, S);
    vq_final<<<1, 1, 0, stream>>>(S, out);
}

// Round 9
// 113.900 us; speedup vs baseline: 2.6436x; 2.6436x over previous
//
#include <hip/hip_runtime.h>
#include <hip/hip_bf16.h>

#define C 128
#define HW 4096
#define NPOS 65536
#define K 1024
#define MB 128           // positions per block
#define NBLK (NPOS/MB)   // 512
#define RS 136           // zt padded row stride in bf16 elems (272 B)
#define RSB 320          // codebook image row stride BYTES (64B-aligned segments)
#define CHK 64           // codes per chunk
#define NCH (K/CHK)      // 16
#define CHB (CHK*RSB)    // 20480 bytes per chunk
#define NRM_OFF 327680   // fp32 norm table offset within img (4 KB)

#define ZQ_OFF 0
#define LOSS_OFF 8388608
#define IDX_OFF 8388609
#define COMMIT_OFF 8454145
#define CODE_OFF 8454146

#define WS_IMG_OFF 8192  // codebook image at d_ws + 8192: 320 KB rows + 4 KB norms

// LDS pad: oversizing the USED zt array is DCE-proof (r8's separate pad array
// was eliminated). Total LDS ~58.3 KB > 53.3 KB -> max 2 blocks/CU ->
// 2 waves/EU -> compiler VGPR budget 256 (the whole point; see r8 post-mortem:
// budget = pool / LDS-derived waves-per-EU, attributes don't raise it).
#define ZT_PAD 9728      // extra u16 elems = 19456 B

typedef __bf16 bf16x8 __attribute__((ext_vector_type(8)));
typedef float f32x4 __attribute__((ext_vector_type(4)));
typedef unsigned short u16x8 __attribute__((ext_vector_type(8)));

// Padded bf16 codebook image: row k = 128 bf16 at 320B stride; norms
// ||e_k||^2+1 in a separate contiguous fp32 table at NRM_OFF (staged to LDS).
// Block 0 zeroes the loss accumulator (replaces the memset dispatch).
__global__ void vq_prep(const float* __restrict__ emb, unsigned char* __restrict__ img,
                        float* __restrict__ S) {
    int k = blockIdx.x;
    int l = threadIdx.x;            // 64 threads
    if (k == 0 && l == 0) S[0] = 0.0f;
    float v0 = emb[k * C + l];
    float v1 = emb[k * C + 64 + l];
    __hip_bfloat16 h0 = __float2bfloat16(v0);
    __hip_bfloat16 h1 = __float2bfloat16(v1);
    unsigned short* row = (unsigned short*)(img + (size_t)k * RSB);
    row[l] = *(unsigned short*)&h0;
    row[64 + l] = *(unsigned short*)&h1;
    float s = v0 * v0 + v1 * v1;
    #pragma unroll
    for (int off = 32; off; off >>= 1) s += __shfl_down(s, off);
    if (l == 0) *(float*)(img + NRM_OFF + (size_t)k * 4) = s + 1.0f;
}

// 256 threads (4 waves, 2M x 2N): wave owns 64 pos x 32 codes. A-tile =
// 4x4 frags = 64 VGPRs, asm-pinned resident (no remat, and with budget 256
// no spill). B read global->VGPR with depth-1 register prefetch; zero
// barriers in the chunk loop.
__global__ __launch_bounds__(256)
void vq_main(const float* __restrict__ z, const float* __restrict__ emb,
             const unsigned char* __restrict__ img,
             float* __restrict__ out, float* __restrict__ S) {
    __shared__ __align__(16) unsigned short zt[MB * RS + ZT_PAD];  // 54272 B (pad: see above)
    __shared__ __align__(16) float norm_lds[K];                    // 4096 B
    __shared__ unsigned int wbest[2][MB];                          // 1024 B
    __shared__ unsigned short idxs[MB];                            // 256 B
    __shared__ float lred[4];

    const int t = threadIdx.x;
    const int w = t >> 6;
    const int lane = t & 63;
    const int nn = lane & 15;      // MFMA: A row m / B col n / C col
    const int q = lane >> 4;       // quad
    const int wm = w >> 1;         // M-half: positions wm*64..+63
    const int wn = w & 1;          // N-half: codes wn*32..+31 of each chunk

    const int blk = blockIdx.x;
    const int n0g = blk * MB;
    const int b = n0g >> 12;
    const int hw0 = n0g & (HW - 1);
    const float* zg = z + (size_t)b * C * HW + hw0;

    // stage norms -> LDS (4 KB, one 16B global_load_lds per lane per wave)
    __builtin_amdgcn_global_load_lds(
        (const __attribute__((address_space(1))) unsigned int*)(img + NRM_OFF + w * 1024 + lane * 16),
        (__attribute__((address_space(3))) unsigned int*)((unsigned char*)norm_lds + w * 1024),
        16, 0, 0);

    // stage z tile -> LDS bf16 [pos][c]: float4 along pos, register transpose
    {
        const int pos4 = (t & 31) * 4;
        const int c0 = (t >> 5) * 16;   // 8 groups x 16 channels
        float4 fv[16];
        #pragma unroll
        for (int i = 0; i < 16; ++i)
            fv[i] = *(const float4*)&zg[(size_t)(c0 + i) * HW + pos4];
        #pragma unroll
        for (int j = 0; j < 4; ++j) {
            u16x8 p0, p1;
            #pragma unroll
            for (int i = 0; i < 8; ++i) {
                float f0 = (j == 0) ? fv[i].x : (j == 1) ? fv[i].y
                         : (j == 2) ? fv[i].z : fv[i].w;
                float f1 = (j == 0) ? fv[8 + i].x : (j == 1) ? fv[8 + i].y
                         : (j == 2) ? fv[8 + i].z : fv[8 + i].w;
                __hip_bfloat16 h0 = __float2bfloat16(f0);
                __hip_bfloat16 h1 = __float2bfloat16(f1);
                p0[i] = *(unsigned short*)&h0;
                p1[i] = *(unsigned short*)&h1;
            }
            *(u16x8*)&zt[(pos4 + j) * RS + c0] = p0;
            *(u16x8*)&zt[(pos4 + j) * RS + c0 + 8] = p1;
        }
    }
    __syncthreads();   // covers zt ds_writes AND norm global_load_lds drain

    // A fragments: 4 M-tiles x 4 K-steps = 64 VGPRs, pinned resident
    bf16x8 a[4][4];
    #pragma unroll
    for (int mt = 0; mt < 4; ++mt)
        #pragma unroll
        for (int ks = 0; ks < 4; ++ks) {
            a[mt][ks] = *(bf16x8*)&zt[(wm * 64 + mt * 16 + nn) * RS + ks * 32 + q * 8];
            asm volatile("" : "+v"(*(f32x4*)&a[mt][ks]));
        }

    unsigned int best[4][4];
    #pragma unroll
    for (int mt = 0; mt < 4; ++mt)
        #pragma unroll
        for (int r = 0; r < 4; ++r) best[mt][r] = 0xFFFFFFFFu;

    // per-lane B pointers: lane (nn,q) reads quarter-row q of codes
    // wn*32+nn (nt=0) and wn*32+16+nn (nt=1)
    const unsigned char* pb0 = img + (size_t)(wn * 32 + nn) * RSB + q * 16;
    const unsigned char* pb1 = pb0 + (size_t)16 * RSB;

    // depth-1 register pipeline: load chunk 0, then each iter prefetch ch+1
    bf16x8 b0[4], b1[4];
    #pragma unroll
    for (int ks = 0; ks < 4; ++ks) {
        b0[ks] = *(const bf16x8*)(pb0 + ks * 64);
        b1[ks] = *(const bf16x8*)(pb1 + ks * 64);
    }

    for (int ch = 0; ch < NCH; ++ch) {
        const int step = (ch + 1 < NCH) ? CHB : 0;
        bf16x8 n0[4], n1[4];
        #pragma unroll
        for (int ks = 0; ks < 4; ++ks) {
            n0[ks] = *(const bf16x8*)(pb0 + step + ks * 64);
            n1[ks] = *(const bf16x8*)(pb1 + step + ks * 64);
        }
        const float en0 = norm_lds[ch * CHK + wn * 32 + nn];
        const float en1 = norm_lds[ch * CHK + wn * 32 + 16 + nn];
        const unsigned int code0 = (unsigned int)(ch * CHK + wn * 32 + nn);

        f32x4 acc0[4], acc1[4];
        #pragma unroll
        for (int mt = 0; mt < 4; ++mt) {
            acc0[mt] = (f32x4){0.f, 0.f, 0.f, 0.f};
            acc1[mt] = (f32x4){0.f, 0.f, 0.f, 0.f};
        }
        #pragma unroll
        for (int ks = 0; ks < 4; ++ks)
            #pragma unroll
            for (int mt = 0; mt < 4; ++mt) {
                acc0[mt] = __builtin_amdgcn_mfma_f32_16x16x32_bf16(a[mt][ks], b0[ks], acc0[mt], 0, 0, 0);
                acc1[mt] = __builtin_amdgcn_mfma_f32_16x16x32_bf16(a[mt][ks], b1[ks], acc1[mt], 0, 0, 0);
            }

        // packed argmin: score' = (enorm+1) - 2*dot (always ~1.0 > 0),
        // clear low 10 mantissa bits, OR in code; u32 min == float min + tie-low.
        #pragma unroll
        for (int mt = 0; mt < 4; ++mt)
            #pragma unroll
            for (int r = 0; r < 4; ++r) {
                float s0 = fmaf(acc0[mt][r], -2.0f, en0);
                float s1 = fmaf(acc1[mt][r], -2.0f, en1);
                unsigned int u0 = (__float_as_uint(s0) & ~1023u) | code0;
                unsigned int u1 = (__float_as_uint(s1) & ~1023u) | (code0 + 16u);
                best[mt][r] = min(best[mt][r], min(u0, u1));
            }

        #pragma unroll
        for (int ks = 0; ks < 4; ++ks) { b0[ks] = n0[ks]; b1[ks] = n1[ks]; }
        pb0 += CHB; pb1 += CHB;
    }

    // in-wave reduce over the 16 code-columns (xor lanes 1,2,4,8 stay in quad)
    #pragma unroll
    for (int mt = 0; mt < 4; ++mt)
        #pragma unroll
        for (int r = 0; r < 4; ++r) {
            unsigned int v = best[mt][r];
            v = min(v, (unsigned int)__shfl_xor((int)v, 1));
            v = min(v, (unsigned int)__shfl_xor((int)v, 2));
            v = min(v, (unsigned int)__shfl_xor((int)v, 4));
            v = min(v, (unsigned int)__shfl_xor((int)v, 8));
            if (nn == 0) wbest[wn][wm * 64 + mt * 16 + q * 4 + r] = v;
        }
    __syncthreads();

    if (t < MB) {
        unsigned int v = min(wbest[0][t], wbest[1][t]);
        unsigned int code = v & 1023u;
        idxs[t] = (unsigned short)code;
        out[IDX_OFF + n0g + t] = (float)code;
    }
    __syncthreads();

    // epilogue: per-position emb gather, register transpose, float4 z_q
    // stores along pos, exact fp32 loss from the same bf16 zt values
    {
        const int pos4 = (t & 31) * 4;
        const int c0 = (t >> 5) * 16;
        float* og = out + ZQ_OFF + (size_t)b * C * HW + hw0;
        float ev[4][16];
        float ls = 0.f;
        #pragma unroll
        for (int j = 0; j < 4; ++j) {
            const int pos = pos4 + j;
            const float* erow = emb + (size_t)idxs[pos] * C;
            #pragma unroll
            for (int g = 0; g < 4; ++g) {
                float4 e = *(const float4*)&erow[c0 + g * 4];
                ev[j][g * 4 + 0] = e.x; ev[j][g * 4 + 1] = e.y;
                ev[j][g * 4 + 2] = e.z; ev[j][g * 4 + 3] = e.w;
            }
            u16x8 z0 = *(u16x8*)&zt[pos * RS + c0];
            u16x8 z1 = *(u16x8*)&zt[pos * RS + c0 + 8];
            #pragma unroll
            for (int i = 0; i < 8; ++i) {
                float zf0 = __uint_as_float((unsigned int)z0[i] << 16);
                float zf1 = __uint_as_float((unsigned int)z1[i] << 16);
                float d0 = zf0 - ev[j][i];
                float d1 = zf1 - ev[j][8 + i];
                ls += d0 * d0 + d1 * d1;
            }
        }
        #pragma unroll
        for (int i = 0; i < 16; ++i) {
            float4 v = { ev[0][i], ev[1][i], ev[2][i], ev[3][i] };
            *(float4*)&og[(size_t)(c0 + i) * HW + pos4] = v;
        }
        #pragma unroll
        for (int off = 32; off; off >>= 1) ls += __shfl_down(ls, off);
        if (lane == 0) lred[w] = ls;
    }
    __syncthreads();
    if (t == 0) atomicAdd(S, lred[0] + lred[1] + lred[2] + lred[3]);
}

__global__ void vq_final(const float* __restrict__ S, float* __restrict__ out) {
    float s = *S;
    out[LOSS_OFF] = 1.25f * s;
    out[COMMIT_OFF] = 0.25f * s;
    out[CODE_OFF] = s;
}

extern "C" void kernel_launch(void* const* d_in, const int* in_sizes, int n_in,
                              void* d_out, int out_size, void* d_ws, size_t ws_size,
                              hipStream_t stream) {
    const float* z = (const float*)d_in[0];
    const float* emb = (const float*)d_in[1];
    float* out = (float*)d_out;
    float* S = (float*)d_ws;
    unsigned char* img = (unsigned char*)d_ws + WS_IMG_OFF;   // needs ~340 KB of ws

    vq_prep<<<K, 64, 0, stream>>>(emb, img, S);
    vq_main<<<NBLK, 256, 0, stream>>>(z, emb, img, out, S);
    vq_final<<<1, 1, 0, stream>>>(S, out);
}